// Round 7
// baseline (375.458 us; speedup 1.0000x reference)
//
#include <hip/hip_runtime.h>

// HiPPO-LegT projection: c_t = A c_{t-1} + B f_t, zero init, emit all c_t.
// Closed form (zero init): causal convolution out[t][s][n] = sum_{j<=t}
// K_{t-j}[n] f[s][j], K_i = A^i B  =>  ONE causal GEMM (M=2048, N=512*64,
// K<=512 triangular).
//
// R4 LESSON: scattered direct loads = txn-bound. R6 LESSON: fragment-pre-
// tiled A + direct loads works. R2/R3/R5/R6 LESSON: every LDS-staged W
// variant lands at the same ~68 us (barrier drains dominate, m233 regime).
// R7: pre-tile W too -> Wt[tau][fn][kq] 1KB fragment tiles (one dwordx4
// per wave = 16 fully-used 64B lines). Gemm has NO LDS and NO barriers:
// K-loop = {8 coalesced global loads + 16 MFMA}, per-wave exact causal
// bound KQ = tau/32+1. Each block does TWO bm tiles (2nd pass B-reads are
// guaranteed L2 hits); grid is bm-fast so sibling blocks of one bn are
// dispatched adjacently (cross-block L2/L3 reuse).
//
// Pipeline:
// 1 squares_fh: block 0: SqT[k]=(A^{2^k})^T (serial mul64 chain);
//   blocks 1..256: f32->f16 cast into tiled fh_t[mtile][kq][l15][quad].
// 2 kvec_fill: 64 blocks x 8 waves; wave computes K_i (binary-exp mat-vec
//   chain) -> compact f32 table Lf[n][z] = K_{511-z}[n].
// 3 wt_fill: 8192 blocks; materialize causal fragment tiles
//   Wt[((tau*4+fn)*16+kq)*512 + l15*32+quad*8 + u] = (j<=tau)?K_{tau-j}[n]:0,
//   j = kq*32+quad*8+u, n = fn*16+l15. Skips tiles with kq*32 > tau.
// 4 causal_gemm: grid (8 bm-pairs, 256 bn) heavy-first, 256 thr, 4 waves.

typedef _Float16 half8  __attribute__((ext_vector_type(8)));
typedef float    f32x4  __attribute__((ext_vector_type(4)));

#define SEQN 2048
#define LT   512

// ---------------------------------------------------------------------------
// 64x64 f32 matmul in LDS: C = X*Y given XT (X transposed) and Y.
// 512 threads, 4x2 output per thread. Writes outT (=C^T) / outN; in-place ok.
__device__ __forceinline__ void mul64(const float* XT, const float* Y,
                                      float* outT, float* outN, int t) {
  const int r = (t >> 5) * 4;
  const int c = (t & 31) * 2;
  float a00 = 0.f, a01 = 0.f, a10 = 0.f, a11 = 0.f;
  float a20 = 0.f, a21 = 0.f, a30 = 0.f, a31 = 0.f;
#pragma unroll 4
  for (int l = 0; l < 64; ++l) {
    const float4 x = *(const float4*)(XT + l * 64 + r);
    const float2 y = *(const float2*)(Y + l * 64 + c);
    a00 += x.x * y.x; a01 += x.x * y.y;
    a10 += x.y * y.x; a11 += x.y * y.y;
    a20 += x.z * y.x; a21 += x.z * y.y;
    a30 += x.w * y.x; a31 += x.w * y.y;
  }
  __syncthreads();
  if (outT) {
    outT[(c + 0) * 64 + r + 0] = a00; outT[(c + 1) * 64 + r + 0] = a01;
    outT[(c + 0) * 64 + r + 1] = a10; outT[(c + 1) * 64 + r + 1] = a11;
    outT[(c + 0) * 64 + r + 2] = a20; outT[(c + 1) * 64 + r + 2] = a21;
    outT[(c + 0) * 64 + r + 3] = a30; outT[(c + 1) * 64 + r + 3] = a31;
  }
  if (outN) {
    outN[(r + 0) * 64 + c + 0] = a00; outN[(r + 0) * 64 + c + 1] = a01;
    outN[(r + 1) * 64 + c + 0] = a10; outN[(r + 1) * 64 + c + 1] = a11;
    outN[(r + 2) * 64 + c + 0] = a20; outN[(r + 2) * 64 + c + 1] = a21;
    outN[(r + 3) * 64 + c + 0] = a30; outN[(r + 3) * 64 + c + 1] = a31;
  }
  __syncthreads();
}

// Block 0: SqT[k][m*64+n] = (A^{2^k})[n][m], k=0..8 (serial squaring chain).
// Blocks 1..256: f32 -> f16 cast into TILED fh_t:
//   fh_t[((row>>4)*16 + (k>>5))*512 + (row&15)*32 + (k&31)]
__global__ __launch_bounds__(512) void squares_fh(
    const float* __restrict__ A, const float* __restrict__ f,
    float* __restrict__ SqT, _Float16* __restrict__ fh_t) {
  __shared__ float S[4096];    // current power, normal
  __shared__ float STr[4096];  // current power, transposed
  const int t = threadIdx.x;
  if (blockIdx.x == 0) {
    for (int i = t; i < 4096; i += 512) {
      const float v = A[i];
      S[i] = v;
      STr[(i & 63) * 64 + (i >> 6)] = v;
    }
    __syncthreads();
    for (int i = t; i < 4096; i += 512) SqT[i] = STr[i];  // k=0
    for (int k = 1; k < 9; ++k) {
      mul64(STr, S, STr, S, t);  // S = S*S (both forms)
      for (int i = t; i < 4096; i += 512) SqT[k * 4096 + i] = STr[i];
    }
  } else {
    const int g = (blockIdx.x - 1) * 512 + t;  // 8-half chunk id, 0..131071
    const int row = g >> 6, kc = g & 63;       // kc: which 8-half chunk of k
    const float4* s = (const float4*)(f + (size_t)row * LT + kc * 8);
    const float4 a = s[0], b = s[1];
    half8 v;
    v[0] = (_Float16)a.x; v[1] = (_Float16)a.y;
    v[2] = (_Float16)a.z; v[3] = (_Float16)a.w;
    v[4] = (_Float16)b.x; v[5] = (_Float16)b.y;
    v[6] = (_Float16)b.z; v[7] = (_Float16)b.w;
    const int off = ((row >> 4) * 16 + (kc >> 2)) * 512 + (row & 15) * 32 +
                    (kc & 3) * 8;
    *(half8*)(fh_t + off) = v;
  }
}

// 64 blocks x 512 threads: group g (wave) computes K_i, i = 8*blk + g, by
// chaining mat-vecs K = A^{2^k} K over set bits of i (commuting powers).
// Writes compact f32 table Lf[n][z] = K_{511-z}[n]  (n-major, 64 x 512).
__global__ __launch_bounds__(512) void kvec_fill(
    const float* __restrict__ SqT, const float* __restrict__ B,
    float* __restrict__ Lf) {
  __shared__ float Kb[8][64];
  const int t = threadIdx.x;
  const int b = blockIdx.x;
  const int g = t >> 6, n = t & 63;
  const int i = b * 8 + g;
  float kreg = B[n];
  for (int k = 0; k < 9; ++k) {
    Kb[g][n] = kreg;
    __syncthreads();
    if ((i >> k) & 1) {  // uniform per wave
      const float* Sk = SqT + k * 4096 + n;  // column n, SqT[m*64+n]=A[n][m]
      float s = 0.f;
#pragma unroll 16
      for (int m = 0; m < 64; ++m) s += Sk[m * 64] * Kb[g][m];
      kreg = s;
    }
    __syncthreads();
  }
  Lf[n * 512 + 511 - i] = kreg;
}

// Materialize causal fragment-ordered weight tiles.
// Block b: tau = b>>4, kq = b&15; skip if kq*32 > tau (never read).
// Thread: fn = t>>6, chunk c = t&63 -> (l15=c>>2, quad=c&3); writes 8 halves.
// Element u: j = kq*32+quad*8+u, n = fn*16+l15,
//   val = (j<=tau) ? K_{tau-j}[n] : 0  ==  (z<512) ? Lf[n][z] : 0,
//   z = 511-tau+j  (8 contiguous f32 reads per thread, L2-resident table).
__global__ __launch_bounds__(256) void wt_fill(const float* __restrict__ Lf,
                                               _Float16* __restrict__ Wt) {
  const int b = blockIdx.x;
  const int tau = b >> 4, kq = b & 15;
  if (kq * 32 > tau) return;
  const int t = threadIdx.x;
  const int fn = t >> 6, c = t & 63;
  const int l15 = c >> 2, quad = c & 3;
  const int n = fn * 16 + l15;
  const int o = 511 - tau + kq * 32 + quad * 8;
  const float* src = Lf + n * 512;
  half8 v;
#pragma unroll
  for (int u = 0; u < 8; ++u) {
    const int z = o + u;
    v[u] = (z < 512) ? (_Float16)src[z] : (_Float16)0.f;
  }
  *(half8*)(Wt + ((size_t)(tau * 4 + fn) * 16 + kq) * 512 + l15 * 32 +
            quad * 8) = v;
}

// Causal GEMM, no LDS, no barriers. Grid (8 bm-pairs, 256 bn), 256 threads.
// 4 waves 2x2 (wm, wn); wave tau = 2bn+wn, 64x64 out per pass via 4x4 of
// 16x16x32 f16 MFMA; per-wave exact causal K bound KQ = tau/32+1.
// Two bm passes per block: pass 1 re-reads the same B tiles -> L2 hits.
__global__ __launch_bounds__(256) void causal_gemm(
    const _Float16* __restrict__ fh_t, const _Float16* __restrict__ Wt,
    float* __restrict__ out) {
  const int bmp = blockIdx.x;             // 0..7: bm pair
  const int bn = 255 - (int)blockIdx.y;   // heavy (large-K) blocks first
  const int lane = threadIdx.x & 63, wid = threadIdx.x >> 6;
  const int wm = wid >> 1, wn = wid & 1;
  const int l15 = lane & 15, quad = lane >> 4;
  const int tau = 2 * bn + wn;
  const int KQ = (tau >> 5) + 1;  // exact causal extent in 32-wide steps
  const int lo = l15 * 32 + quad * 8;

  // B fragment base: frag (fn,kq) at pw + (fn*16+kq)*512
  const _Float16* pw = Wt + (size_t)tau * 64 * 512 + lo;

#pragma unroll
  for (int pass = 0; pass < 2; ++pass) {
    const int bm = bmp * 2 + pass;
    // A fragment base: frag (fm,kq) at px + fm*8192 + kq*512
    const _Float16* px = fh_t + (size_t)(bm * 8 + wm * 4) * 8192 + lo;

    f32x4 acc[4][4];
    const f32x4 z4 = {0.f, 0.f, 0.f, 0.f};
#pragma unroll
    for (int i = 0; i < 4; ++i)
#pragma unroll
      for (int j = 0; j < 4; ++j) acc[i][j] = z4;

    for (int kq = 0; kq < KQ; ++kq) {
      half8 av[4], bv[4];
#pragma unroll
      for (int fm = 0; fm < 4; ++fm)
        av[fm] = *(const half8*)(px + fm * 8192 + kq * 512);
#pragma unroll
      for (int fn = 0; fn < 4; ++fn)
        bv[fn] = *(const half8*)(pw + (fn * 16 + kq) * 512);
#pragma unroll
      for (int fm = 0; fm < 4; ++fm)
#pragma unroll
        for (int fn = 0; fn < 4; ++fn)
          acc[fm][fn] = __builtin_amdgcn_mfma_f32_16x16x32_f16(
              av[fm], bv[fn], acc[fm][fn], 0, 0, 0);
    }

    // epilogue: D row = quad*4+reg (seq), col = lane&15 (n)
#pragma unroll
    for (int fm = 0; fm < 4; ++fm) {
#pragma unroll
      for (int rr = 0; rr < 4; ++rr) {
        const size_t row = (size_t)tau * SEQN +
                           (bm * 128 + wm * 64 + fm * 16 + quad * 4 + rr);
        float* o = out + row * 64 + l15;
#pragma unroll
        for (int fn = 0; fn < 4; ++fn) o[fn * 16] = acc[fm][fn][rr];
      }
    }
  }
}

extern "C" void kernel_launch(void* const* d_in, const int* in_sizes, int n_in,
                              void* d_out, int out_size, void* d_ws,
                              size_t ws_size, hipStream_t stream) {
  const float* f = (const float*)d_in[0];  // (16,128,512) -> (2048, 512)
  const float* A = (const float*)d_in[1];  // (64,64)
  const float* B = (const float*)d_in[2];  // (64,)
  float* out = (float*)d_out;              // (512, 2048, 64)

  // workspace layout
  _Float16* Wt = (_Float16*)d_ws;                       // 512*64*512*2 = 32 MB
  char* p = (char*)d_ws + (32 << 20);
  float* Lf = (float*)p;                                // 64*512*4 = 128 KB
  float* SqT = (float*)(p + (128 << 10));               // 9*4096*4 = 144 KB
  _Float16* fh_t = (_Float16*)(p + (320 << 10));        // 2048*512*2 = 2 MB

  squares_fh<<<257, 512, 0, stream>>>(A, f, SqT, fh_t);
  kvec_fill<<<64, 512, 0, stream>>>(SqT, B, Lf);
  wt_fill<<<8192, 256, 0, stream>>>(Lf, Wt);
  causal_gemm<<<dim3(8, 256), 256, 0, stream>>>(fh_t, Wt, out);
}